// Round 1
// baseline (3808.374 us; speedup 1.0000x reference)
//
#include <hip/hip_runtime.h>
#include <cstddef>

#define EN 800000
#define VN 50000

// ---- LDS layout (float offsets) ----
#define L_WH1R16 0        // 17   : Wh1 row 16
#define L_WMU1   17       // 136  : Wmu1 [17][8]
#define L_BS1    153      // 64
#define L_WS1E   217      // 1024 : Ws1 rows 128..143  [16][64]
#define L_WS1V   1241     // 1088 : Ws1 rows 144..160  [17][64]
#define L_WG1    2329     // 512  : Wg1 [64][8]
#define L_BG1    2841     // 8
#define L_L23    2849     // two layer blocks follow
// within a layer block:
#define LB_WH    0        // 64   : Wh [8][8]
#define LB_WS    64       // 4608 : Ws [72][64]
#define LB_BS    4672     // 64
#define LB_WMU   4736     // 64   : Wmu [8][8]
#define LB_WG    4800     // 512  : Wg [64][8]
#define LB_BG    5312     // 8
#define LB_SIZE  5320
#define L_TOT    (L_L23 + 2*LB_SIZE)   // 13489 floats = ~54 KB

// ---------------- node precompute ----------------
// A[v][j]  = sum_k s[v][k] * Ws1[k][j]        (rows 0..63)
// B[v][j]  = sum_k s[v][k] * Ws1[64+k][j]     (rows 64..127)
// VA[v][r*17+h] = sum_d V[v][r][d] * Wh1[d][h]      (rows 0..7)
// VB[v][r*17+h] = sum_d V[v][r][d] * Wh1[8+d][h]    (rows 8..15)
// VA/VB padded to stride 52 for float4 loads.
__global__ __launch_bounds__(64) void node_pre(
    const float* __restrict__ s, const float* __restrict__ V,
    const float* __restrict__ Wh1, const float* __restrict__ Ws1,
    float* __restrict__ A, float* __restrict__ B,
    float* __restrict__ VA, float* __restrict__ VB)
{
    int v = blockIdx.x;
    int lane = threadIdx.x;
    const float* sv = s + (size_t)v * 64;
    float a = 0.f, b = 0.f;
    #pragma unroll 8
    for (int k = 0; k < 64; ++k) {
        float sk = sv[k];
        a += sk * Ws1[k * 64 + lane];
        b += sk * Ws1[(64 + k) * 64 + lane];
    }
    A[(size_t)v * 64 + lane] = a;
    B[(size_t)v * 64 + lane] = b;

    if (lane < 51) {
        int r = lane / 17, h = lane % 17;
        const float* vv = V + (size_t)v * 24 + r * 8;
        float va = 0.f, vb = 0.f;
        #pragma unroll
        for (int d = 0; d < 8; ++d) {
            float x = vv[d];
            va += x * Wh1[d * 17 + h];
            vb += x * Wh1[(8 + d) * 17 + h];
        }
        VA[(size_t)v * 52 + lane] = va;
        VB[(size_t)v * 52 + lane] = vb;
    }
}

// ---------------- fused edge kernel ----------------
__global__ __launch_bounds__(256) void edge_kernel(
    const float* __restrict__ s_e, const float* __restrict__ V_e,
    const int* __restrict__ eidx,
    const float* __restrict__ Wh1, const float* __restrict__ Ws1, const float* __restrict__ bs1,
    const float* __restrict__ Wmu1, const float* __restrict__ Wg1, const float* __restrict__ bg1,
    const float* __restrict__ Wh2, const float* __restrict__ Ws2, const float* __restrict__ bs2,
    const float* __restrict__ Wmu2, const float* __restrict__ Wg2, const float* __restrict__ bg2,
    const float* __restrict__ Wh3, const float* __restrict__ Ws3, const float* __restrict__ bs3,
    const float* __restrict__ Wmu3, const float* __restrict__ Wg3, const float* __restrict__ bg3,
    const float* __restrict__ A, const float* __restrict__ B,
    const float* __restrict__ VA, const float* __restrict__ VB,
    float* __restrict__ out)
{
    __shared__ float lds[L_TOT];
    const int tid = threadIdx.x;

    // cooperative weight staging
    for (int i = tid; i < 17;   i += 256) lds[L_WH1R16 + i] = Wh1[16 * 17 + i];
    for (int i = tid; i < 136;  i += 256) lds[L_WMU1 + i] = Wmu1[i];
    for (int i = tid; i < 64;   i += 256) lds[L_BS1 + i] = bs1[i];
    for (int i = tid; i < 1024; i += 256) lds[L_WS1E + i] = Ws1[128 * 64 + i];
    for (int i = tid; i < 1088; i += 256) lds[L_WS1V + i] = Ws1[144 * 64 + i];
    for (int i = tid; i < 512;  i += 256) lds[L_WG1 + i] = Wg1[i];
    for (int i = tid; i < 8;    i += 256) lds[L_BG1 + i] = bg1[i];
    for (int i = tid; i < 64;   i += 256) { lds[L_L23 + LB_WH  + i] = Wh2[i];  lds[L_L23 + LB_SIZE + LB_WH  + i] = Wh3[i]; }
    for (int i = tid; i < 4608; i += 256) { lds[L_L23 + LB_WS  + i] = Ws2[i];  lds[L_L23 + LB_SIZE + LB_WS  + i] = Ws3[i]; }
    for (int i = tid; i < 64;   i += 256) { lds[L_L23 + LB_BS  + i] = bs2[i];  lds[L_L23 + LB_SIZE + LB_BS  + i] = bs3[i]; }
    for (int i = tid; i < 64;   i += 256) { lds[L_L23 + LB_WMU + i] = Wmu2[i]; lds[L_L23 + LB_SIZE + LB_WMU + i] = Wmu3[i]; }
    for (int i = tid; i < 512;  i += 256) { lds[L_L23 + LB_WG  + i] = Wg2[i];  lds[L_L23 + LB_SIZE + LB_WG  + i] = Wg3[i]; }
    for (int i = tid; i < 8;    i += 256) { lds[L_L23 + LB_BG  + i] = bg2[i];  lds[L_L23 + LB_SIZE + LB_BG  + i] = bg3[i]; }
    __syncthreads();

    const int e = blockIdx.x * 256 + tid;
    const int src = eidx[e];
    const int dst = eidx[EN + e];

    // ---------- Layer 1: vector path ----------
    float va[52], vb[52];
    {
        const float4* qa = (const float4*)(VA + (size_t)src * 52);
        const float4* qb = (const float4*)(VB + (size_t)dst * 52);
        #pragma unroll
        for (int q = 0; q < 13; ++q) {
            float4 ta = qa[q], tb = qb[q];
            va[4*q] = ta.x; va[4*q+1] = ta.y; va[4*q+2] = ta.z; va[4*q+3] = ta.w;
            vb[4*q] = tb.x; vb[4*q+1] = tb.y; vb[4*q+2] = tb.z; vb[4*q+3] = tb.w;
        }
    }
    const float ve0 = V_e[(size_t)e * 3 + 0];
    const float ve1 = V_e[(size_t)e * 3 + 1];
    const float ve2 = V_e[(size_t)e * 3 + 2];

    float vn[17];
    float vmu[3][8];
    #pragma unroll
    for (int o = 0; o < 8; ++o) { vmu[0][o] = 0.f; vmu[1][o] = 0.f; vmu[2][o] = 0.f; }
    #pragma unroll
    for (int h = 0; h < 17; ++h) {
        float w  = lds[L_WH1R16 + h];
        float v0 = va[h]      + vb[h]      + ve0 * w;
        float v1 = va[17 + h] + vb[17 + h] + ve1 * w;
        float v2 = va[34 + h] + vb[34 + h] + ve2 * w;
        vn[h] = sqrtf(v0 * v0 + v1 * v1 + v2 * v2 + 1e-8f);
        #pragma unroll
        for (int o = 0; o < 8; ++o) {
            float wm = lds[L_WMU1 + h * 8 + o];
            vmu[0][o] += v0 * wm; vmu[1][o] += v1 * wm; vmu[2][o] += v2 * wm;
        }
    }

    // ---------- Layer 1: scalar path ----------
    float so[64];
    {
        const float4* fa = (const float4*)(A + (size_t)src * 64);
        const float4* fb = (const float4*)(B + (size_t)dst * 64);
        #pragma unroll
        for (int q = 0; q < 16; ++q) {
            float4 ta = fa[q], tb = fb[q];
            so[4*q]   = ta.x + tb.x + lds[L_BS1 + 4*q];
            so[4*q+1] = ta.y + tb.y + lds[L_BS1 + 4*q+1];
            so[4*q+2] = ta.z + tb.z + lds[L_BS1 + 4*q+2];
            so[4*q+3] = ta.w + tb.w + lds[L_BS1 + 4*q+3];
        }
    }
    {
        const float* pse = s_e + (size_t)e * 16;
        for (int k = 0; k < 16; ++k) {         // rolled: multiplicand from global (L1-cached)
            float m = pse[k];
            #pragma unroll
            for (int j = 0; j < 64; ++j) so[j] += m * lds[L_WS1E + k * 64 + j];
        }
    }
    #pragma unroll
    for (int k = 0; k < 17; ++k) {
        float m = vn[k];
        #pragma unroll
        for (int j = 0; j < 64; ++j) so[j] += m * lds[L_WS1V + k * 64 + j];
    }

    // gate1 (uses pre-relu s_out), then relu in place
    float g[8];
    #pragma unroll
    for (int o = 0; o < 8; ++o) g[o] = lds[L_BG1 + o];
    #pragma unroll
    for (int j = 0; j < 64; ++j) {
        float sj = so[j];
        #pragma unroll
        for (int o = 0; o < 8; ++o) g[o] += sj * lds[L_WG1 + j * 8 + o];
    }
    float Vv[3][8];
    #pragma unroll
    for (int o = 0; o < 8; ++o) {
        float gg = 1.f / (1.f + __expf(-g[o]));
        Vv[0][o] = vmu[0][o] * gg; Vv[1][o] = vmu[1][o] * gg; Vv[2][o] = vmu[2][o] * gg;
    }
    #pragma unroll
    for (int j = 0; j < 64; ++j) so[j] = fmaxf(so[j], 0.f);

    // ---------- Layers 2 & 3 (shared code, runtime LDS base) ----------
    #pragma unroll 1
    for (int layer = 0; layer < 2; ++layer) {
        const int base = L_L23 + layer * LB_SIZE;

        float vn2[8];
        float vmu2[3][8];
        #pragma unroll
        for (int o = 0; o < 8; ++o) { vmu2[0][o] = 0.f; vmu2[1][o] = 0.f; vmu2[2][o] = 0.f; }
        #pragma unroll
        for (int h = 0; h < 8; ++h) {
            float v0 = 0.f, v1 = 0.f, v2 = 0.f;
            #pragma unroll
            for (int d = 0; d < 8; ++d) {
                float w = lds[base + LB_WH + d * 8 + h];
                v0 += Vv[0][d] * w; v1 += Vv[1][d] * w; v2 += Vv[2][d] * w;
            }
            vn2[h] = sqrtf(v0 * v0 + v1 * v1 + v2 * v2 + 1e-8f);
            #pragma unroll
            for (int o = 0; o < 8; ++o) {
                float wm = lds[base + LB_WMU + h * 8 + o];
                vmu2[0][o] += v0 * wm; vmu2[1][o] += v1 * wm; vmu2[2][o] += v2 * wm;
            }
        }

        float acc[64];
        #pragma unroll
        for (int j = 0; j < 64; ++j) acc[j] = lds[base + LB_BS + j];
        #pragma unroll
        for (int k = 0; k < 64; ++k) {
            float m = so[k];
            #pragma unroll
            for (int j = 0; j < 64; ++j) acc[j] += m * lds[base + LB_WS + k * 64 + j];
        }
        #pragma unroll
        for (int k = 0; k < 8; ++k) {
            float m = vn2[k];
            #pragma unroll
            for (int j = 0; j < 64; ++j) acc[j] += m * lds[base + LB_WS + (64 + k) * 64 + j];
        }

        float g2[8];
        #pragma unroll
        for (int o = 0; o < 8; ++o) g2[o] = lds[base + LB_BG + o];
        #pragma unroll
        for (int j = 0; j < 64; ++j) {
            float sj = acc[j];
            #pragma unroll
            for (int o = 0; o < 8; ++o) g2[o] += sj * lds[base + LB_WG + j * 8 + o];
        }
        #pragma unroll
        for (int o = 0; o < 8; ++o) {
            float gg = 1.f / (1.f + __expf(-g2[o]));
            Vv[0][o] = vmu2[0][o] * gg; Vv[1][o] = vmu2[1][o] * gg; Vv[2][o] = vmu2[2][o] * gg;
        }
        if (layer == 0) {
            #pragma unroll
            for (int j = 0; j < 64; ++j) so[j] = fmaxf(acc[j], 0.f);
        } else {
            #pragma unroll
            for (int j = 0; j < 64; ++j) so[j] = acc[j];   // no relu on layer 3
        }
    }

    // ---------- write outputs: s3 [E,64] then V3 [E,3,8] ----------
    {
        float4* po = (float4*)(out + (size_t)e * 64);
        #pragma unroll
        for (int q = 0; q < 16; ++q) {
            float4 t; t.x = so[4*q]; t.y = so[4*q+1]; t.z = so[4*q+2]; t.w = so[4*q+3];
            po[q] = t;
        }
        float4* pv = (float4*)(out + (size_t)EN * 64 + (size_t)e * 24);
        #pragma unroll
        for (int r = 0; r < 3; ++r) {
            float4 t; t.x = Vv[r][0]; t.y = Vv[r][1]; t.z = Vv[r][2]; t.w = Vv[r][3];
            pv[2*r] = t;
            float4 u; u.x = Vv[r][4]; u.y = Vv[r][5]; u.z = Vv[r][6]; u.w = Vv[r][7];
            pv[2*r+1] = u;
        }
    }
}

extern "C" void kernel_launch(void* const* d_in, const int* in_sizes, int n_in,
                              void* d_out, int out_size, void* d_ws, size_t ws_size,
                              hipStream_t stream)
{
    const float* s    = (const float*)d_in[0];
    const float* V    = (const float*)d_in[1];
    const float* s_e  = (const float*)d_in[2];
    const float* V_e  = (const float*)d_in[3];
    const int*   eidx = (const int*)d_in[4];
    const float* Wh1 = (const float*)d_in[5];
    const float* Ws1 = (const float*)d_in[6];
    const float* bs1 = (const float*)d_in[7];
    const float* Wmu1= (const float*)d_in[8];
    const float* Wg1 = (const float*)d_in[9];
    const float* bg1 = (const float*)d_in[10];
    const float* Wh2 = (const float*)d_in[11];
    const float* Ws2 = (const float*)d_in[12];
    const float* bs2 = (const float*)d_in[13];
    const float* Wmu2= (const float*)d_in[14];
    const float* Wg2 = (const float*)d_in[15];
    const float* bg2 = (const float*)d_in[16];
    const float* Wh3 = (const float*)d_in[17];
    const float* Ws3 = (const float*)d_in[18];
    const float* bs3 = (const float*)d_in[19];
    const float* Wmu3= (const float*)d_in[20];
    const float* Wg3 = (const float*)d_in[21];
    const float* bg3 = (const float*)d_in[22];

    float* ws = (float*)d_ws;
    float* A  = ws;                       // 50000*64 = 3,200,000 floats
    float* B  = A + 3200000;              // 3,200,000
    float* VA = B + 3200000;              // 50000*52 = 2,600,000
    float* VB = VA + 2600000;             // 2,600,000  (total ~46.4 MB)
    float* out = (float*)d_out;

    hipLaunchKernelGGL(node_pre, dim3(VN), dim3(64), 0, stream,
                       s, V, Wh1, Ws1, A, B, VA, VB);
    hipLaunchKernelGGL(edge_kernel, dim3(EN / 256), dim3(256), 0, stream,
                       s_e, V_e, eidx,
                       Wh1, Ws1, bs1, Wmu1, Wg1, bg1,
                       Wh2, Ws2, bs2, Wmu2, Wg2, bg2,
                       Wh3, Ws3, bs3, Wmu3, Wg3, bg3,
                       A, B, VA, VB, out);
}

// Round 3
// 1309.425 us; speedup vs baseline: 2.9084x; 2.9084x over previous
//
#include <hip/hip_runtime.h>
#include <cstddef>

#define EN 800000
#define VN 50000

// =====================================================================
// node_pre: per-node precompute.
//   A[v][j]      = sum_k s[v][k]   * Ws1[k][j]       (rows 0..63)
//   B[v][j]      = sum_k s[v][k]   * Ws1[64+k][j]    (rows 64..127)
//   VA[v][h*3+r] = sum_d V[v][r][d]* Wh1[d][h]       (rows 0..7)   h-major!
//   VB[v][h*3+r] = sum_d V[v][r][d]* Wh1[8+d][h]     (rows 8..15)
// One wave per node iteration: s-row/V-row are wave-uniform -> SGPR,
// weights live per-lane in VGPRs (column `lane`).
// =====================================================================
__global__ __launch_bounds__(256) void node_pre(
    const float* __restrict__ s, const float* __restrict__ V,
    const float* __restrict__ Wh1, const float* __restrict__ Ws1,
    float* __restrict__ A, float* __restrict__ B,
    float* __restrict__ VA, float* __restrict__ VB)
{
    const int tid  = threadIdx.x;
    const int lane = tid & 63;
    const int wv   = __builtin_amdgcn_readfirstlane(tid >> 6);

    // per-lane weight column of Ws1 rows 0..127
    float w[128];
    #pragma unroll
    for (int k = 0; k < 128; ++k) w[k] = Ws1[k * 64 + lane];

    // per-lane vector-path weights (lanes 0..50; h-major: lane = h*3+r)
    const int hv = (lane < 51) ? (lane / 3) : 0;
    const int rv = (lane < 51) ? (lane % 3) : 0;
    float whA[8], whB[8];
    #pragma unroll
    for (int d = 0; d < 8; ++d) {
        whA[d] = Wh1[d * 17 + hv];
        whB[d] = Wh1[(8 + d) * 17 + hv];
    }

    const int nwaves = gridDim.x * 4;
    for (int v = blockIdx.x * 4 + wv; v < VN; v += nwaves) {
        const float* sv = s + (size_t)v * 64;          // uniform -> s_load
        float a = 0.f, b = 0.f;
        #pragma unroll
        for (int k = 0; k < 64; ++k) {
            float sk = sv[k];
            a += sk * w[k];
            b += sk * w[64 + k];
        }
        A[(size_t)v * 64 + lane] = a;
        B[(size_t)v * 64 + lane] = b;

        const float* vrow = V + (size_t)v * 24 + rv * 8;
        float va = 0.f, vb = 0.f;
        #pragma unroll
        for (int d = 0; d < 8; ++d) {
            float x = vrow[d];
            va += x * whA[d];
            vb += x * whB[d];
        }
        if (lane < 51) {
            VA[(size_t)v * 52 + lane] = va;
            VB[(size_t)v * 52 + lane] = vb;
        }
    }
}

// =====================================================================
// edge_kernel: one thread per edge. Per-edge multiplicand vectors live in
// an LDS column (wbuf[k][lane]) so matmul k-loops stay ROLLED (runtime k)
// with zero scratch. Weights are read with wave-uniform indices -> the
// compiler emits s_load + v_fmac with SGPR weight operand (no LDS, no
// per-lane weight traffic). Accumulators acc[64] stay in VGPRs (static j).
// LDS: 4 waves * 72 rows * 64 lanes * 4B = 72 KB -> 2 blocks/CU.
// =====================================================================
__global__ __launch_bounds__(256, 2) void edge_kernel(
    const float* __restrict__ s_e, const float* __restrict__ V_e,
    const int* __restrict__ eidx,
    const float* __restrict__ Wh1, const float* __restrict__ Ws1, const float* __restrict__ bs1,
    const float* __restrict__ Wmu1, const float* __restrict__ Wg1, const float* __restrict__ bg1,
    const float* __restrict__ Wh2, const float* __restrict__ Ws2, const float* __restrict__ bs2,
    const float* __restrict__ Wmu2, const float* __restrict__ Wg2, const float* __restrict__ bg2,
    const float* __restrict__ Wh3, const float* __restrict__ Ws3, const float* __restrict__ bs3,
    const float* __restrict__ Wmu3, const float* __restrict__ Wg3, const float* __restrict__ bg3,
    const float* __restrict__ A, const float* __restrict__ B,
    const float* __restrict__ VA, const float* __restrict__ VB,
    float* __restrict__ out)
{
    __shared__ float buf[4][72][64];
    const int tid  = threadIdx.x;
    const int lane = tid & 63;
    const int wv   = tid >> 6;
    float (*wbuf)[64] = buf[wv];

    const int e   = blockIdx.x * 256 + tid;
    const int src = eidx[e];
    const int dst = eidx[EN + e];

    // ---------------- Layer 1: vector path ----------------
    const float ve0 = V_e[(size_t)e * 3 + 0];
    const float ve1 = V_e[(size_t)e * 3 + 1];
    const float ve2 = V_e[(size_t)e * 3 + 2];

    float vmu[24];
    #pragma unroll
    for (int o = 0; o < 24; ++o) vmu[o] = 0.f;

    const float4* qa  = (const float4*)(VA + (size_t)src * 52);
    const float4* qb  = (const float4*)(VB + (size_t)dst * 52);
    const float*  w16 = Wh1 + 16 * 17;

    #pragma unroll 1
    for (int c = 0; c < 4; ++c) {          // h = 4c .. 4c+3 (h-major chunks)
        float4 a0 = qa[3*c], a1 = qa[3*c+1], a2 = qa[3*c+2];
        float4 b0 = qb[3*c], b1 = qb[3*c+1], b2 = qb[3*c+2];
        float av[12] = {a0.x,a0.y,a0.z,a0.w, a1.x,a1.y,a1.z,a1.w, a2.x,a2.y,a2.z,a2.w};
        float bv[12] = {b0.x,b0.y,b0.z,b0.w, b1.x,b1.y,b1.z,b1.w, b2.x,b2.y,b2.z,b2.w};
        #pragma unroll
        for (int i = 0; i < 4; ++i) {
            const int h = 4*c + i;
            float ww = w16[h];                               // uniform
            float v0 = av[3*i+0] + bv[3*i+0] + ve0 * ww;
            float v1 = av[3*i+1] + bv[3*i+1] + ve1 * ww;
            float v2 = av[3*i+2] + bv[3*i+2] + ve2 * ww;
            wbuf[h][lane] = sqrtf(v0*v0 + v1*v1 + v2*v2 + 1e-8f);
            const float* wm = Wmu1 + h * 8;                  // uniform
            #pragma unroll
            for (int o = 0; o < 8; ++o) {
                float m = wm[o];
                vmu[o] += v0 * m; vmu[8+o] += v1 * m; vmu[16+o] += v2 * m;
            }
        }
    }
    {   // h = 16 (elements 48..50; 51 is pad)
        float4 a = qa[12], b = qb[12];
        float ww = w16[16];
        float v0 = a.x + b.x + ve0 * ww;
        float v1 = a.y + b.y + ve1 * ww;
        float v2 = a.z + b.z + ve2 * ww;
        wbuf[16][lane] = sqrtf(v0*v0 + v1*v1 + v2*v2 + 1e-8f);
        const float* wm = Wmu1 + 16 * 8;
        #pragma unroll
        for (int o = 0; o < 8; ++o) {
            float m = wm[o];
            vmu[o] += v0 * m; vmu[8+o] += v1 * m; vmu[16+o] += v2 * m;
        }
    }

    // ---------------- Layer 1: scalar path ----------------
    float acc[64];
    {
        const float4* fa = (const float4*)(A + (size_t)src * 64);
        const float4* fb = (const float4*)(B + (size_t)dst * 64);
        #pragma unroll
        for (int q = 0; q < 16; ++q) {
            float4 ta = fa[q], tb = fb[q];
            acc[4*q+0] = ta.x + tb.x + bs1[4*q+0];
            acc[4*q+1] = ta.y + tb.y + bs1[4*q+1];
            acc[4*q+2] = ta.z + tb.z + bs1[4*q+2];
            acc[4*q+3] = ta.w + tb.w + bs1[4*q+3];
        }
    }
    // s_e @ Ws1 rows 128..143  (weight row uniform -> SGPR; m per-lane)
    const float* pse = s_e + (size_t)e * 16;
    #pragma unroll 1
    for (int k = 0; k < 16; ++k) {
        float m = pse[k];
        const float* wr = Ws1 + (128 + k) * 64;
        #pragma unroll
        for (int j = 0; j < 64; ++j) acc[j] += m * wr[j];
    }
    // vn @ Ws1 rows 144..160  (vn from LDS column)
    #pragma unroll 1
    for (int k = 0; k < 17; ++k) {
        float m = wbuf[k][lane];
        const float* wr = Ws1 + (144 + k) * 64;
        #pragma unroll
        for (int j = 0; j < 64; ++j) acc[j] += m * wr[j];
    }

    // gate1 (pre-relu acc), vector gating, relu -> LDS rows 0..63
    float Vv[24];
    {
        float g[8];
        #pragma unroll
        for (int o = 0; o < 8; ++o) g[o] = bg1[o];
        #pragma unroll
        for (int j = 0; j < 64; ++j) {
            float sj = acc[j];
            const float* wg = Wg1 + j * 8;
            #pragma unroll
            for (int o = 0; o < 8; ++o) g[o] += sj * wg[o];
        }
        #pragma unroll
        for (int o = 0; o < 8; ++o) {
            float gg = 1.f / (1.f + __expf(-g[o]));
            Vv[o] = vmu[o] * gg; Vv[8+o] = vmu[8+o] * gg; Vv[16+o] = vmu[16+o] * gg;
        }
    }
    #pragma unroll
    for (int j = 0; j < 64; ++j) wbuf[j][lane] = fmaxf(acc[j], 0.f);

    // ---------------- Layers 2 & 3 ----------------
    #pragma unroll 1
    for (int t = 0; t < 2; ++t) {
        const float* Wh  = t ? Wh3  : Wh2;
        const float* Ws  = t ? Ws3  : Ws2;
        const float* bs  = t ? bs3  : bs2;
        const float* Wmu = t ? Wmu3 : Wmu2;
        const float* Wg  = t ? Wg3  : Wg2;
        const float* bg  = t ? bg3  : bg2;

        float vmu2[24];
        #pragma unroll
        for (int o = 0; o < 24; ++o) vmu2[o] = 0.f;
        #pragma unroll 1
        for (int h = 0; h < 8; ++h) {
            float v0 = 0.f, v1 = 0.f, v2 = 0.f;
            #pragma unroll
            for (int d = 0; d < 8; ++d) {
                float wd = Wh[d * 8 + h];                    // uniform
                v0 += Vv[d] * wd; v1 += Vv[8+d] * wd; v2 += Vv[16+d] * wd;
            }
            wbuf[64 + h][lane] = sqrtf(v0*v0 + v1*v1 + v2*v2 + 1e-8f);
            const float* wm = Wmu + h * 8;
            #pragma unroll
            for (int o = 0; o < 8; ++o) {
                float m = wm[o];
                vmu2[o] += v0 * m; vmu2[8+o] += v1 * m; vmu2[16+o] += v2 * m;
            }
        }

        #pragma unroll
        for (int j = 0; j < 64; ++j) acc[j] = bs[j];
        #pragma unroll 1
        for (int k = 0; k < 72; ++k) {                       // 64 s + 8 vn rows
            float m = wbuf[k][lane];
            const float* wr = Ws + k * 64;
            #pragma unroll
            for (int j = 0; j < 64; ++j) acc[j] += m * wr[j];
        }

        float g[8];
        #pragma unroll
        for (int o = 0; o < 8; ++o) g[o] = bg[o];
        #pragma unroll
        for (int j = 0; j < 64; ++j) {
            float sj = acc[j];
            const float* wg = Wg + j * 8;
            #pragma unroll
            for (int o = 0; o < 8; ++o) g[o] += sj * wg[o];
        }
        #pragma unroll
        for (int o = 0; o < 8; ++o) {
            float gg = 1.f / (1.f + __expf(-g[o]));
            Vv[o] = vmu2[o] * gg; Vv[8+o] = vmu2[8+o] * gg; Vv[16+o] = vmu2[16+o] * gg;
        }
        if (t == 0) {
            #pragma unroll
            for (int j = 0; j < 64; ++j) wbuf[j][lane] = fmaxf(acc[j], 0.f);
        }
    }

    // ---------------- outputs: s3 [E,64], V3 [E,3,8] ----------------
    float4* po = (float4*)(out + (size_t)e * 64);
    #pragma unroll
    for (int q = 0; q < 16; ++q) {
        float4 tq; tq.x = acc[4*q]; tq.y = acc[4*q+1]; tq.z = acc[4*q+2]; tq.w = acc[4*q+3];
        po[q] = tq;
    }
    float4* pv = (float4*)(out + (size_t)EN * 64 + (size_t)e * 24);
    #pragma unroll
    for (int q = 0; q < 6; ++q) {
        float4 tq; tq.x = Vv[4*q]; tq.y = Vv[4*q+1]; tq.z = Vv[4*q+2]; tq.w = Vv[4*q+3];
        pv[q] = tq;
    }
}

extern "C" void kernel_launch(void* const* d_in, const int* in_sizes, int n_in,
                              void* d_out, int out_size, void* d_ws, size_t ws_size,
                              hipStream_t stream)
{
    const float* s    = (const float*)d_in[0];
    const float* V    = (const float*)d_in[1];
    const float* s_e  = (const float*)d_in[2];
    const float* V_e  = (const float*)d_in[3];
    const int*   eidx = (const int*)d_in[4];
    const float* Wh1 = (const float*)d_in[5];
    const float* Ws1 = (const float*)d_in[6];
    const float* bs1 = (const float*)d_in[7];
    const float* Wmu1= (const float*)d_in[8];
    const float* Wg1 = (const float*)d_in[9];
    const float* bg1 = (const float*)d_in[10];
    const float* Wh2 = (const float*)d_in[11];
    const float* Ws2 = (const float*)d_in[12];
    const float* bs2 = (const float*)d_in[13];
    const float* Wmu2= (const float*)d_in[14];
    const float* Wg2 = (const float*)d_in[15];
    const float* bg2 = (const float*)d_in[16];
    const float* Wh3 = (const float*)d_in[17];
    const float* Ws3 = (const float*)d_in[18];
    const float* bs3 = (const float*)d_in[19];
    const float* Wmu3= (const float*)d_in[20];
    const float* Wg3 = (const float*)d_in[21];
    const float* bg3 = (const float*)d_in[22];

    float* ws  = (float*)d_ws;
    float* A   = ws;                      // 50000*64
    float* B   = A + 3200000;             // 50000*64
    float* VA  = B + 3200000;             // 50000*52 (h-major, padded)
    float* VB  = VA + 2600000;            // 50000*52
    float* out = (float*)d_out;

    hipLaunchKernelGGL(node_pre, dim3(512), dim3(256), 0, stream,
                       s, V, Wh1, Ws1, A, B, VA, VB);
    hipLaunchKernelGGL(edge_kernel, dim3(EN / 256), dim3(256), 0, stream,
                       s_e, V_e, eidx,
                       Wh1, Ws1, bs1, Wmu1, Wg1, bg1,
                       Wh2, Ws2, bs2, Wmu2, Wg2, bg2,
                       Wh3, Ws3, bs3, Wmu3, Wg3, bg3,
                       A, B, VA, VB, out);
}